// Round 5
// baseline (503.943 us; speedup 1.0000x reference)
//
#include <hip/hip_runtime.h>
#include <hip/hip_bf16.h>
#include <cstdint>

// ---------------------------------------------------------------------------
// TempoSpikeSelfAttention on MI355X (gfx950), bf16-MFMA pipeline.
//   dims: T=4 B=4 N=1024 D=768 H=12 Dh=64 -> M = T*B*N = 16384 rows
// Pipeline:
//   1. cast x, Wq|Wk|Wv (concat), Wo to bf16
//   2. gemm_rp QKV: 128x256 tile, wave=128x64, mfma 32x32x16. A staged in LDS
//      (reg-pipelined, stride-36 pad), B-frags DIRECT from global (weights sit
//      in L2) prefetched 1 kt ahead. V column-slab written transposed to Vt
//      in the epilogue (transpose kernel eliminated). Q,K slabs written flat.
//   3. attn32 v4 (unchanged): grid (192,4) same-XCD q-tiles, reg-pipelined
//      K/V staging, permlane32-swap P transform, L1-norm in regs.
//   4. gemm_rp O: out = CTX @ Wo^T + bo -> fp32 d_out
// ---------------------------------------------------------------------------

typedef __attribute__((ext_vector_type(8))) short short8;     // 8 bf16 = 4 VGPR
typedef __attribute__((ext_vector_type(16))) float float16v;  // 32x32 acc

__device__ __forceinline__ unsigned short f2bf(float f) {
  unsigned int u = __float_as_uint(f);
  u = (u + 0x7fffu + ((u >> 16) & 1u)) >> 16;   // RNE
  return (unsigned short)u;
}

// pack two f32 -> two bf16 (round-half-away) in one v_perm_b32
__device__ __forceinline__ unsigned int pkbf(float a, float b) {
  unsigned int ua = __float_as_uint(a) + 0x8000u;
  unsigned int ub = __float_as_uint(b) + 0x8000u;
  return __builtin_amdgcn_perm(ub, ua, 0x07060302u);  // [bf(a) lo16 | bf(b) hi16]
}

// ---------------------------------------------------------------------------
__global__ __launch_bounds__(256) void cast4(const float* __restrict__ src,
                                             unsigned short* __restrict__ dst,
                                             int n4) {
  int i = blockIdx.x * 256 + threadIdx.x;
  if (i >= n4) return;
  float4 f = reinterpret_cast<const float4*>(src)[i];
  ushort4 o;
  o.x = f2bf(f.x); o.y = f2bf(f.y); o.z = f2bf(f.z); o.w = f2bf(f.w);
  reinterpret_cast<ushort4*>(dst)[i] = o;
}

// ---------------------------------------------------------------------------
// C[i,j] = sum_k A[i,k]*Bt[j,k] + bias[j].  K=768. Tile 128(M) x 256(N).
// 4 waves; wave w owns cols [w*64, w*64+64), all 128 rows. mfma 32x32x16.
// A: LDS, stride 36 els, reg-pipelined (2 barriers/kt, loads in flight across
// compute). B: per-wave frags loaded directly from global (L2-resident
// weights), prefetched one kt ahead into registers. 24 kt iterations.
// FUSE_VT: col-slab [1536,2304) is written transposed to vt (per-head d-major)
// instead of flat.
template <bool OUT_BF16, bool FUSE_VT>
__global__ __launch_bounds__(256) void gemm_rp(
    const unsigned short* __restrict__ A,   // [M,768] bf16
    const unsigned short* __restrict__ Bt,  // [N,768] bf16
    unsigned short* __restrict__ Cb,        // bf16 out [M,N]
    float* __restrict__ Cf,                 // f32 out  [M,N]
    unsigned short* __restrict__ vtout,     // [(tb*12+h)*64+d][1024]
    const float* __restrict__ b0, const float* __restrict__ b1,
    const float* __restrict__ b2, int N) {
  constexpr int K = 768;
  __shared__ unsigned short As[128 * 36];   // stride 36 els (72 B): 2-way max

  const int tid = threadIdx.x, lane = tid & 63, w = tid >> 6;
  const int l31 = lane & 31, hl = lane >> 5;
  const int j0 = blockIdx.x * 256, i0 = blockIdx.y * 128;

  // A staging: thread covers rows (tid>>2) and (tid>>2)+64, 16B chunk (tid&3)
  const int ar = tid >> 2, ak = (tid & 3) * 8;
  const unsigned short* ga = A + (size_t)(i0 + ar) * K + ak;
  // B frags: [ct*2+ks] -> row j0 + w*64 + ct*32 + l31, k = kt*32+ks*16+hl*8
  const unsigned short* gb = Bt + (size_t)(j0 + w * 64 + l31) * K + hl * 8;

  float16v acc[4][2];   // [rt][ct]
#pragma unroll
  for (int rt = 0; rt < 4; ++rt)
#pragma unroll
    for (int ct = 0; ct < 2; ++ct)
#pragma unroll
      for (int i = 0; i < 16; ++i) acc[rt][ct][i] = 0.f;

  uint4 a_st[2], a_nx[2], b_st[4], b_nx[4];
  a_st[0] = *(const uint4*)ga;
  a_st[1] = *(const uint4*)(ga + 64 * K);
#pragma unroll
  for (int ct = 0; ct < 2; ++ct)
#pragma unroll
    for (int ks = 0; ks < 2; ++ks)
      b_st[ct * 2 + ks] = *(const uint4*)(gb + (size_t)ct * 32 * K + ks * 16);
#pragma unroll
  for (int i = 0; i < 2; ++i) a_nx[i] = a_st[i];
#pragma unroll
  for (int i = 0; i < 4; ++i) b_nx[i] = b_st[i];

#pragma unroll 1
  for (int kt = 0; kt < 24; ++kt) {
    __syncthreads();   // all reads of previous A tile done
    *(uint4*)&As[ar * 36 + ak] = a_st[0];          // waits vmcnt for a_st
    *(uint4*)&As[(ar + 64) * 36 + ak] = a_st[1];
    __syncthreads();   // A tile visible
    if (kt < 23) {     // issue next-tile loads; drain at next iter's barrier
      const unsigned short* ga2 = ga + (kt + 1) * 32;
      a_nx[0] = *(const uint4*)ga2;
      a_nx[1] = *(const uint4*)(ga2 + 64 * K);
      const unsigned short* gb2 = gb + (kt + 1) * 32;
#pragma unroll
      for (int ct = 0; ct < 2; ++ct)
#pragma unroll
        for (int ks = 0; ks < 2; ++ks)
          b_nx[ct * 2 + ks] =
              *(const uint4*)(gb2 + (size_t)ct * 32 * K + ks * 16);
    }
#pragma unroll
    for (int ks = 0; ks < 2; ++ks) {
      short8 af[4];
#pragma unroll
      for (int rt = 0; rt < 4; ++rt)
        af[rt] = *(const short8*)&As[(rt * 32 + l31) * 36 + ks * 16 + hl * 8];
#pragma unroll
      for (int rt = 0; rt < 4; ++rt)
#pragma unroll
        for (int ct = 0; ct < 2; ++ct) {
          union { uint4 u; short8 s; } bf;
          bf.u = b_st[ct * 2 + ks];
          acc[rt][ct] = __builtin_amdgcn_mfma_f32_32x32x16_bf16(
              af[rt], bf.s, acc[rt][ct], 0, 0, 0);
        }
    }
    // rotate (compiler waits on loads here, at end of compute)
#pragma unroll
    for (int i = 0; i < 2; ++i) a_st[i] = a_nx[i];
#pragma unroll
    for (int i = 0; i < 4; ++i) b_st[i] = b_nx[i];
  }

  // ---- epilogue. C: row = i0 + rt*32 + (reg&3)+8*(reg>>2)+4*hl, col per ct.
  const int sel = FUSE_VT ? (blockIdx.x / 3) : 0;   // 256-col tiles, 3 per 768
  const float* bp = (sel == 0) ? b0 : ((sel == 1) ? b1 : b2);
#pragma unroll
  for (int ct = 0; ct < 2; ++ct) {
    const int cgl = j0 + w * 64 + ct * 32 + l31;
    const float bias = bp[cgl - sel * 768];
    if (FUSE_VT && sel == 2) {
      // V slab -> vt[(tb*12+h)*64 + d][n], b64-packed along n
      const int h = (cgl - 1536) >> 6, d = cgl & 63;
      const int tb = i0 >> 10, nb = i0 & 1023;
      unsigned short* vrow = vtout + ((size_t)(tb * 12 + h) * 64 + d) * 1024;
#pragma unroll
      for (int rt = 0; rt < 4; ++rt)
#pragma unroll
        for (int g = 0; g < 4; ++g) {
          const float v0 = acc[rt][ct][4 * g + 0] + bias;
          const float v1 = acc[rt][ct][4 * g + 1] + bias;
          const float v2 = acc[rt][ct][4 * g + 2] + bias;
          const float v3 = acc[rt][ct][4 * g + 3] + bias;
          uint2 u;
          u.x = pkbf(v0, v1);
          u.y = pkbf(v2, v3);
          *(uint2*)&vrow[nb + rt * 32 + g * 8 + hl * 4] = u;
        }
    } else {
#pragma unroll
      for (int rt = 0; rt < 4; ++rt)
#pragma unroll
        for (int reg = 0; reg < 16; ++reg) {
          const int r = i0 + rt * 32 + (reg & 3) + 8 * (reg >> 2) + 4 * hl;
          const float v = acc[rt][ct][reg] + bias;
          if (OUT_BF16)
            Cb[(size_t)r * N + cgl] = f2bf(v);
          else
            Cf[(size_t)r * N + cgl] = v;
        }
    }
  }
}

// ---------------------------------------------------------------------------
// Attention v4. Grid (tbh=192, qt=4); 256 thr = 4 waves; wave = 64 q (2 x 32).
// Per kv-tile (64 keys):
//   barrier#1 (drains loads of kv) -> ds_write staged regs -> barrier#2 ->
//   issue loads kv+1 (hidden under compute) -> compute:
//     S^T = K.Q^T  (A=K rows from LDS, B=Q regs; C: row=kv, col=q=l31)
//     relu -> den (reg, q=l31); pack bf16; permlane32_swap -> PV B-frags
//     octx += V^T.P (A=Vt rows from LDS, B=P frags; C: row=d, col=q=l31)
__global__ __launch_bounds__(256) void attn32(
    const unsigned short* __restrict__ qkv,  // [16384, 2304] bf16
    const unsigned short* __restrict__ vt,   // [(tbh)*64 + d][1024] bf16
    unsigned short* __restrict__ ctx) {      // [16384, 768] bf16
  __shared__ unsigned short Ks[64 * 72];     // [kv_local][d], padded
  __shared__ unsigned short Vs[64 * 72];     // [d][kv_local], padded

  const int tbh = blockIdx.x;                // same-head blocks: ids 192 apart
  const int qt = blockIdx.y;                 // -> same XCD (192 % 8 == 0)
  const int tb = tbh / 12, h = tbh % 12;
  const int tid = threadIdx.x, lane = tid & 63, w = tid >> 6;
  const int l31 = lane & 31, hl = lane >> 5;

  // ---- Q fragments: one-time scattered global loads ----
  short8 qf[2][4];   // [qs][kc]: B-op: lane holds Q[q=.. +l31][kc*16+hl*8+j]
#pragma unroll
  for (int qs = 0; qs < 2; ++qs) {
    const unsigned short* qp =
        qkv + (size_t)(tb * 1024 + qt * 256 + w * 64 + qs * 32 + l31) * 2304 +
        h * 64 + hl * 8;
#pragma unroll
    for (int kc = 0; kc < 4; ++kc) qf[qs][kc] = *(const short8*)(qp + kc * 16);
  }

  // ---- staging: 256 thr cover 64 rows x 8 chunks of 16B, 2 rows/thread ----
  const int srow = tid >> 3;   // 0..31 (and +32)
  const int sblk = tid & 7;
  const unsigned short* kcol =
      qkv + (size_t)(tb * 1024) * 2304 + 768 + h * 64 + sblk * 8;
  const unsigned short* vcol = vt + ((size_t)tbh * 64 + srow) * 1024 + sblk * 8;
  uint4 kr0, kr1, vr0, vr1;
  auto loadKV = [&](int kv) {
    const unsigned short* kp = kcol + (size_t)(kv * 64 + srow) * 2304;
    kr0 = *(const uint4*)kp;
    kr1 = *(const uint4*)(kp + 32 * 2304);
    const unsigned short* vp = vcol + kv * 64;
    vr0 = *(const uint4*)vp;
    vr1 = *(const uint4*)(vp + 32 * 1024);
  };

  float16v octx[2][2];   // [qs][dt]; C: row=d_local, col=q=l31
#pragma unroll
  for (int qs = 0; qs < 2; ++qs)
#pragma unroll
    for (int dt = 0; dt < 2; ++dt)
#pragma unroll
      for (int i = 0; i < 16; ++i) octx[qs][dt][i] = 0.f;
  float den[2] = {0.f, 0.f};

  loadKV(0);

#pragma unroll 1
  for (int kv = 0; kv < 16; ++kv) {
    __syncthreads();   // #1: all reads of tile kv-1 done; drains loads of kv
    *(uint4*)&Ks[srow * 72 + sblk * 8] = kr0;
    *(uint4*)&Ks[(srow + 32) * 72 + sblk * 8] = kr1;
    *(uint4*)&Vs[srow * 72 + sblk * 8] = vr0;
    *(uint4*)&Vs[(srow + 32) * 72 + sblk * 8] = vr1;
    __syncthreads();   // #2: writes visible (vmcnt trivially 0 here)
    if (kv < 15) loadKV(kv + 1);   // in flight across compute below

#pragma unroll
    for (int qs = 0; qs < 2; ++qs) {
      // S^T = K.Q^T, then relu+den+pack (C: col=q=l31, row=kv=4hl+(r)+8g+32mt)
      unsigned int pk[2][8];   // [mt][g*2+p]
#pragma unroll
      for (int mt = 0; mt < 2; ++mt) {
        float16v st;
#pragma unroll
        for (int i = 0; i < 16; ++i) st[i] = 0.f;
#pragma unroll
        for (int kc = 0; kc < 4; ++kc) {
          short8 kf =
              *(const short8*)&Ks[(mt * 32 + l31) * 72 + kc * 16 + hl * 8];
          st = __builtin_amdgcn_mfma_f32_32x32x16_bf16(kf, qf[qs][kc], st, 0, 0, 0);
        }
#pragma unroll
        for (int g = 0; g < 4; ++g) {
          float v0 = st[4 * g + 0]; v0 = v0 > 0.f ? v0 : 0.f;
          float v1 = st[4 * g + 1]; v1 = v1 > 0.f ? v1 : 0.f;
          float v2 = st[4 * g + 2]; v2 = v2 > 0.f ? v2 : 0.f;
          float v3 = st[4 * g + 3]; v3 = v3 > 0.f ? v3 : 0.f;
          den[qs] += (v0 + v1) + (v2 + v3);
          pk[mt][g * 2 + 0] = pkbf(v0, v1);
          pk[mt][g * 2 + 1] = pkbf(v2, v3);
        }
      }
      // C-layout -> PV B-operand layout entirely in registers:
      // B-frag[kc] lane(l31,hl) needs kv = kc*16 + hl*8 + j at q=l31.
      // X=pk[mt][gb*2+p], Y=pk[mt][(gb+1)*2+p]; permlane32_swap gives
      // X'={X.lo,Y.lo} (j=2p,2p+1), Y'={X.hi,Y.hi} (j=2p+4,2p+5).
#pragma unroll
      for (int kc = 0; kc < 4; ++kc) {
        const int mt = kc >> 1, gb = (kc & 1) * 2;
        unsigned int a0 = pk[mt][gb * 2 + 0], b0 = pk[mt][gb * 2 + 2];
        unsigned int a1 = pk[mt][gb * 2 + 1], b1 = pk[mt][gb * 2 + 3];
        asm("v_permlane32_swap_b32 %0, %1" : "+v"(a0), "+v"(b0));
        asm("v_permlane32_swap_b32 %0, %1" : "+v"(a1), "+v"(b1));
        union { unsigned int u[4]; short8 s; } pf;
        pf.u[0] = a0; pf.u[1] = a1; pf.u[2] = b0; pf.u[3] = b1;
#pragma unroll
        for (int dt = 0; dt < 2; ++dt) {
          short8 vb =
              *(const short8*)&Vs[(dt * 32 + l31) * 72 + kc * 16 + hl * 8];
          octx[qs][dt] = __builtin_amdgcn_mfma_f32_32x32x16_bf16(
              vb, pf.s, octx[qs][dt], 0, 0, 0);
        }
      }
    }
  }

  // ---- normalize + store; lane l31 owns q, all in registers ----
#pragma unroll
  for (int qs = 0; qs < 2; ++qs) {
    float d = den[qs] + __shfl_xor(den[qs], 32);
    const float sc = 1.f / (d + 8e-6f);   // folded 1/sqrt(64) scaling
    const size_t qrow = (size_t)(tb * 1024 + qt * 256 + w * 64 + qs * 32 + l31);
#pragma unroll
    for (int dt = 0; dt < 2; ++dt)
#pragma unroll
      for (int g = 0; g < 4; ++g) {
        const float v0 = octx[qs][dt][4 * g + 0] * sc;
        const float v1 = octx[qs][dt][4 * g + 1] * sc;
        const float v2 = octx[qs][dt][4 * g + 2] * sc;
        const float v3 = octx[qs][dt][4 * g + 3] * sc;
        uint2 u;
        u.x = pkbf(v0, v1);
        u.y = pkbf(v2, v3);
        *(uint2*)&ctx[qrow * 768 + h * 64 + dt * 32 + g * 8 + hl * 4] = u;
      }
  }
}

// ---------------------------------------------------------------------------
extern "C" void kernel_launch(void* const* d_in, const int* in_sizes, int n_in,
                              void* d_out, int out_size, void* d_ws, size_t ws_size,
                              hipStream_t stream) {
  const float* x  = (const float*)d_in[0];
  const float* Wq = (const float*)d_in[1];
  const float* bq = (const float*)d_in[2];
  const float* Wk = (const float*)d_in[3];
  const float* bk = (const float*)d_in[4];
  const float* Wv = (const float*)d_in[5];
  const float* bv = (const float*)d_in[6];
  const float* Wo = (const float*)d_in[7];
  const float* bo = (const float*)d_in[8];
  float* out = (float*)d_out;

  char* ws = (char*)d_ws;
  // workspace layout (bytes); CTX aliases XBF (XBF dead after QKV GEMM)
  unsigned short* XBF  = (unsigned short*)(ws);                  // 25165824 B
  unsigned short* CTX  = (unsigned short*)(ws);                  // alias
  unsigned short* WQKV = (unsigned short*)(ws + 25165824);       //  3538944 B
  unsigned short* WOb  = (unsigned short*)(ws + 28704768);       //  1179648 B
  unsigned short* QKV  = (unsigned short*)(ws + 29884416);       // 75497472 B
  unsigned short* VT   = (unsigned short*)(ws + 105381888);      // 25165824 B
  // total: 130547712 B

  cast4<<<12288, 256, 0, stream>>>(x, XBF, 3145728);
  cast4<<<576, 256, 0, stream>>>(Wq, WQKV, 147456);
  cast4<<<576, 256, 0, stream>>>(Wk, WQKV + 589824, 147456);
  cast4<<<576, 256, 0, stream>>>(Wv, WQKV + 1179648, 147456);
  cast4<<<576, 256, 0, stream>>>(Wo, WOb, 147456);

  // QKV: Q,K flat into QKV; V transposed into VT (flat V slab unwritten)
  gemm_rp<true, true><<<dim3(9, 128), 256, 0, stream>>>(
      XBF, WQKV, QKV, nullptr, VT, bq, bk, bv, 2304);
  attn32<<<dim3(192, 4), 256, 0, stream>>>(QKV, VT, CTX);
  gemm_rp<false, false><<<dim3(3, 128), 256, 0, stream>>>(
      CTX, WOb, nullptr, out, nullptr, bo, bo, bo, 768);
}